// Round 1
// baseline (10436.524 us; speedup 1.0000x reference)
//
#include <hip/hip_runtime.h>
#include <hip/hip_bf16.h>

#define B_  32
#define A_  128
#define T_  64
#define N_  4096        // B_*A_
#define HS  256
#define ES  32
#define RS  64
#define KX  832         // 64 (r) + 512 (e) + 256 (h)
#define GD  1024        // 4*HS

typedef __attribute__((ext_vector_type(8))) short bf8_t;   // 8 x bf16
typedef __attribute__((ext_vector_type(4))) float f4_t;    // mfma acc

__device__ __forceinline__ unsigned short f2bf(float x) {
  union { float f; unsigned u; } v; v.f = x;
  unsigned u = v.u;
  u += 0x7fffu + ((u >> 16) & 1u);     // round-to-nearest-even
  return (unsigned short)(u >> 16);
}
__device__ __forceinline__ float sigm(float x) { return 1.f / (1.f + __expf(-x)); }

// ---------------- build Wcat = [W_ih | W_hh] in bf16, [1024 x 832] row-major
__global__ void k_wcat(const float* __restrict__ W_ih, const float* __restrict__ W_hh,
                       unsigned short* __restrict__ Wc) {
  int i = blockIdx.x * 256 + threadIdx.x;
  if (i >= GD * KX) return;
  int m = i / KX, k = i - m * KX;
  float v = (k < 576) ? W_ih[m * 576 + k] : W_hh[m * 256 + (k - 576)];
  Wc[i] = f2bf(v);
}

// ---------------- per step: r = relu(xt @ W_r^T + b_r);  hW = h @ W_e^T
__global__ __launch_bounds__(256) void k_r_hw(
    const float* __restrict__ data, const float* __restrict__ W_r,
    const float* __restrict__ b_r, const float* __restrict__ h,
    const float* __restrict__ W_e, float* __restrict__ rbuf,
    float* __restrict__ hW, unsigned short* __restrict__ Xbf, int t) {
  int blk = blockIdx.x;
  if (blk < 1024) {
    int gid = blk * 256 + threadIdx.x;       // n*64 + l
    int n = gid >> 6, l = gid & 63;
    float x0 = data[(n * T_ + t) * 2 + 0];
    float x1 = data[(n * T_ + t) * 2 + 1];
    float v = fmaxf(x0 * W_r[l * 2] + x1 * W_r[l * 2 + 1] + b_r[l], 0.f);
    rbuf[gid] = v;
    Xbf[n * KX + l] = f2bf(v);
  } else {
    int gid = (blk - 1024) * 256 + threadIdx.x;  // n*32 + c
    int n = gid >> 5, cc = gid & 31;
    const float4* hr = (const float4*)(h + n * HS);
    const float4* we = (const float4*)(W_e + cc * HS);
    float acc = 0.f;
    #pragma unroll 8
    for (int k = 0; k < HS / 4; ++k) {
      float4 a = hr[k], b = we[k];
      acc += a.x * b.x + a.y * b.y + a.z * b.z + a.w * b.w;
    }
    hW[gid] = acc;
  }
}

// ---------------- social: S[b,g,i,c] = sum_j mask * hW[b,j,c];  e = relu(S+b_e)
// written directly into Xbf at the torch-reshape-permuted location.
__global__ __launch_bounds__(256) void k_social(
    const float* __restrict__ data, const float* __restrict__ hW,
    const float* __restrict__ b_e, unsigned short* __restrict__ Xbf, int t) {
  int b  = blockIdx.x >> 4;          // batch
  int ig = blockIdx.x & 15;          // row group (8 rows)
  __shared__ float sx[A_], sy[A_];
  __shared__ float shw[A_ * ES];     // 16 KB
  __shared__ float acc[8][16 * ES];  // 16 KB
  int tid = threadIdx.x;
  if (tid < A_) {
    sx[tid] = data[((b * A_ + tid) * T_ + t) * 2 + 0];
    sy[tid] = data[((b * A_ + tid) * T_ + t) * 2 + 1];
  }
  for (int i = tid; i < A_ * ES; i += 256) shw[i] = hW[b * A_ * ES + i];
  for (int i = tid; i < 8 * 16 * ES; i += 256) ((float*)acc)[i] = 0.f;
  __syncthreads();

  int half = tid >> 5;               // 0..7 : row within group
  int lane = tid & 31;               // c
  int irow = ig * 8 + half;
  float xi = sx[irow], yi = sy[irow];
  float* accr = acc[half];
  if (xi >= 0.f) {
    for (int j = 0; j < A_; ++j) {
      if (j == irow) continue;
      float xj = sx[j];
      if (xj < 0.f) continue;
      float dx = xi - xj, dy = yi - sy[j];
      unsigned bx = 0, by = 0;
      bx |= (dx >= 8.f   && dx <= 16.f) ? 1u : 0u;
      bx |= (dx >= 0.f   && dx <= 8.f ) ? 2u : 0u;
      bx |= (dx >= -8.f  && dx <= 0.f ) ? 4u : 0u;
      bx |= (dx >= -16.f && dx <= -8.f) ? 8u : 0u;
      if (!bx) continue;
      by |= (dy >= -16.f && dy <= -8.f) ? 1u : 0u;
      by |= (dy >= -8.f  && dy <= 0.f ) ? 2u : 0u;
      by |= (dy >= 0.f   && dy <= 8.f ) ? 4u : 0u;
      by |= (dy >= 8.f   && dy <= 16.f) ? 8u : 0u;
      if (!by) continue;
      float hv = shw[j * ES + lane];
      unsigned m16 = 0, ty = by;
      while (ty) { int gy = __ffs(ty) - 1; ty &= ty - 1; m16 |= bx << (gy * 4); }
      while (m16) {
        int g = __ffs(m16) - 1; m16 &= m16 - 1;
        accr[g * ES + lane] += hv;
      }
    }
  }
  // epilogue: e[b,g,irow,c] -> Xbf[b, g*8 + irow>>4, 64 + (irow&15)*32 + c]
  float be = b_e[lane];
  int hi = irow >> 4;
  int klo = (irow & 15) * ES + lane;
  for (int g = 0; g < 16; ++g) {
    float e = fmaxf(accr[g * ES + lane] + be, 0.f);
    int a_out = g * 8 + hi;
    Xbf[(b * A_ + a_out) * KX + 64 + klo] = f2bf(e);
  }
}

// ---------------- gates = Xbf @ Wc^T (bf16 MFMA, fp32 acc), no bias
__global__ __launch_bounds__(256) void k_gemm(
    const unsigned short* __restrict__ Xbf, const unsigned short* __restrict__ Wc,
    float* __restrict__ gates) {
  int w    = blockIdx.x * 4 + (threadIdx.x >> 6);  // global wave id, 4096 waves
  int lane = threadIdx.x & 63;
  int tm = w >> 5, tn = w & 31;                    // 128 x 32 tiles of 32x32
  int row0 = tm * 32, col0 = tn * 32;
  int lr = lane & 15;
  int lk = (lane >> 4) * 8;
  const bf8_t* pa0 = (const bf8_t*)(Xbf + (row0 + lr) * KX + lk);
  const bf8_t* pa1 = (const bf8_t*)(Xbf + (row0 + 16 + lr) * KX + lk);
  const bf8_t* pb0 = (const bf8_t*)(Wc  + (col0 + lr) * KX + lk);
  const bf8_t* pb1 = (const bf8_t*)(Wc  + (col0 + 16 + lr) * KX + lk);
  f4_t a00 = {0.f,0.f,0.f,0.f}, a01 = a00, a10 = a00, a11 = a00;
  for (int kk = 0; kk < KX / 32; ++kk) {
    bf8_t a0 = pa0[kk * 4];
    bf8_t a1 = pa1[kk * 4];
    bf8_t b0 = pb0[kk * 4];
    bf8_t b1 = pb1[kk * 4];
    a00 = __builtin_amdgcn_mfma_f32_16x16x32_bf16(a0, b0, a00, 0, 0, 0);
    a01 = __builtin_amdgcn_mfma_f32_16x16x32_bf16(a0, b1, a01, 0, 0, 0);
    a10 = __builtin_amdgcn_mfma_f32_16x16x32_bf16(a1, b0, a10, 0, 0, 0);
    a11 = __builtin_amdgcn_mfma_f32_16x16x32_bf16(a1, b1, a11, 0, 0, 0);
  }
  int crow = (lane >> 4) * 4, ccol = lane & 15;
  #pragma unroll
  for (int j = 0; j < 4; ++j) {
    gates[(row0 + crow + j) * GD + col0 + ccol]           = a00[j];
    gates[(row0 + crow + j) * GD + col0 + 16 + ccol]      = a01[j];
    gates[(row0 + 16 + crow + j) * GD + col0 + ccol]      = a10[j];
    gates[(row0 + 16 + crow + j) * GD + col0 + 16 + ccol] = a11[j];
  }
}

// ---------------- LSTM pointwise + output head, one block per row n
__global__ __launch_bounds__(256) void k_point_head(
    const float* __restrict__ gates, const float* __restrict__ b_ih,
    const float* __restrict__ b_hh, const float* __restrict__ rbuf,
    float* __restrict__ cbuf, float* __restrict__ hbuf,
    unsigned short* __restrict__ Xbf,
    const float* __restrict__ W_p, const float* __restrict__ b_p,
    const float* __restrict__ W_p2, const float* __restrict__ b_p2,
    const float* __restrict__ W_mu, const float* __restrict__ b_mu,
    const float* __restrict__ W_sd, const float* __restrict__ b_sd,
    const float* __restrict__ W_cr, const float* __restrict__ b_cr,
    float* __restrict__ out, int t) {
  int n = blockIdx.x, q = threadIdx.x;
  __shared__ float sh[HS], sr[RS], sp[64], so[32];
  const float* g = gates + n * GD;
  float ig = g[q]       + b_ih[q]       + b_hh[q];
  float fg = g[q + 256] + b_ih[q + 256] + b_hh[q + 256];
  float gg = g[q + 512] + b_ih[q + 512] + b_hh[q + 512];
  float og = g[q + 768] + b_ih[q + 768] + b_hh[q + 768];
  float c2 = sigm(fg) * cbuf[n * HS + q] + sigm(ig) * tanhf(gg);
  float h2 = sigm(og) * tanhf(c2);
  cbuf[n * HS + q] = c2;
  hbuf[n * HS + q] = h2;
  Xbf[n * KX + 576 + q] = f2bf(h2);
  sh[q] = h2;
  if (q < RS) sr[q] = rbuf[n * RS + q];
  __syncthreads();
  if (q < 64) {
    const float4* wp = (const float4*)(W_p + q * 320);
    float a = b_p[q];
    #pragma unroll 4
    for (int k = 0; k < 16; ++k) {
      float4 wv = wp[k];
      a += sr[4*k]*wv.x + sr[4*k+1]*wv.y + sr[4*k+2]*wv.z + sr[4*k+3]*wv.w;
    }
    #pragma unroll 8
    for (int k = 0; k < 64; ++k) {
      float4 wv = wp[16 + k];
      a += sh[4*k]*wv.x + sh[4*k+1]*wv.y + sh[4*k+2]*wv.z + sh[4*k+3]*wv.w;
    }
    sp[q] = a;
  }
  __syncthreads();
  if (q < 32) {
    const float* w2 = W_p2 + q * 64;
    float a = b_p2[q];
    #pragma unroll 8
    for (int k = 0; k < 64; ++k) a += sp[k] * w2[k];
    so[q] = a;
  }
  __syncthreads();
  if (q < 5) {
    const float* wv; float bv;
    if      (q == 0) { wv = W_mu;      bv = b_mu[0]; }
    else if (q == 1) { wv = W_mu + 32; bv = b_mu[1]; }
    else if (q == 2) { wv = W_sd;      bv = b_sd[0]; }
    else if (q == 3) { wv = W_sd + 32; bv = b_sd[1]; }
    else             { wv = W_cr;      bv = b_cr[0]; }
    float a = bv;
    #pragma unroll 8
    for (int k = 0; k < 32; ++k) a += so[k] * wv[k];
    if      (q < 2) out[(n * T_ + t) * 2 + q] = a;                          // mu
    else if (q < 4) out[N_ * T_ * 2 + (n * T_ + t) * 2 + (q - 2)] = __expf(a); // sd
    else            out[N_ * T_ * 4 + n * T_ + t] = tanhf(a);               // cr
  }
}

extern "C" void kernel_launch(void* const* d_in, const int* in_sizes, int n_in,
                              void* d_out, int out_size, void* d_ws, size_t ws_size,
                              hipStream_t stream) {
  const float* data = (const float*)d_in[0];
  const float* W_r  = (const float*)d_in[2];
  const float* b_r  = (const float*)d_in[3];
  const float* W_e  = (const float*)d_in[4];
  const float* b_e  = (const float*)d_in[5];
  const float* W_ih = (const float*)d_in[6];
  const float* W_hh = (const float*)d_in[7];
  const float* b_ih = (const float*)d_in[8];
  const float* b_hh = (const float*)d_in[9];
  const float* W_p  = (const float*)d_in[10];
  const float* b_p  = (const float*)d_in[11];
  const float* W_p2 = (const float*)d_in[12];
  const float* b_p2 = (const float*)d_in[13];
  const float* W_mu = (const float*)d_in[14];
  const float* b_mu = (const float*)d_in[15];
  const float* W_sd = (const float*)d_in[16];
  const float* b_sd = (const float*)d_in[17];
  const float* W_cr = (const float*)d_in[18];
  const float* b_cr = (const float*)d_in[19];
  float* out = (float*)d_out;

  char* ws = (char*)d_ws;
  float* hbuf  = (float*)(ws);                     // 4 MB
  float* cbuf  = (float*)(ws + (4u  << 20));       // 4 MB
  float* rbuf  = (float*)(ws + (8u  << 20));       // 1 MB
  float* hW    = (float*)(ws + (9u  << 20));       // 0.5 MB
  float* gates = (float*)(ws + (10u << 20));       // 16 MB
  unsigned short* Xbf = (unsigned short*)(ws + (26u << 20)); // 6.8 MB
  unsigned short* Wc  = (unsigned short*)(ws + (34u << 20)); // 1.7 MB

  hipMemsetAsync(hbuf, 0, (size_t)N_ * HS * sizeof(float), stream);
  hipMemsetAsync(cbuf, 0, (size_t)N_ * HS * sizeof(float), stream);
  hipMemsetAsync(Xbf,  0, (size_t)N_ * KX * sizeof(unsigned short), stream);

  k_wcat<<<(GD * KX + 255) / 256, 256, 0, stream>>>(W_ih, W_hh, Wc);

  for (int t = 0; t < T_; ++t) {
    k_r_hw<<<1536, 256, 0, stream>>>(data, W_r, b_r, hbuf, W_e, rbuf, hW, Xbf, t);
    k_social<<<512, 256, 0, stream>>>(data, hW, b_e, Xbf, t);
    k_gemm<<<1024, 256, 0, stream>>>(Xbf, Wc, gates);
    k_point_head<<<4096, 256, 0, stream>>>(gates, b_ih, b_hh, rbuf, cbuf, hbuf, Xbf,
        W_p, b_p, W_p2, b_p2, W_mu, b_mu, W_sd, b_sd, W_cr, b_cr, out, t);
  }
}

// Round 2
// 7334.185 us; speedup vs baseline: 1.4230x; 1.4230x over previous
//
#include <hip/hip_runtime.h>
#include <hip/hip_bf16.h>

#define B_  32
#define A_  128
#define T_  64
#define N_  4096        // B_*A_
#define HS  256
#define ES  32
#define RS  64
#define KX  832         // 64 (r) + 512 (e) + 256 (h)
#define GD  1024        // 4*HS

typedef __attribute__((ext_vector_type(8))) short bf8_t;   // 8 x bf16
typedef __attribute__((ext_vector_type(4))) float f4_t;    // mfma acc

__device__ __forceinline__ unsigned short f2bf(float x) {
  union { float f; unsigned u; } v; v.f = x;
  unsigned u = v.u;
  u += 0x7fffu + ((u >> 16) & 1u);     // round-to-nearest-even
  return (unsigned short)(u >> 16);
}
__device__ __forceinline__ float sigm(float x) { return 1.f / (1.f + __expf(-x)); }

__device__ __forceinline__ void gload16(const void* g, void* l) {
  __builtin_amdgcn_global_load_lds((const __attribute__((address_space(1))) void*)g,
                                   (__attribute__((address_space(3))) void*)l, 16, 0, 0);
}

// ---------------- build Wcat = [W_ih | W_hh] in bf16, [1024 x 832] row-major
__global__ void k_wcat(const float* __restrict__ W_ih, const float* __restrict__ W_hh,
                       unsigned short* __restrict__ Wc) {
  int i = blockIdx.x * 256 + threadIdx.x;
  if (i >= GD * KX) return;
  int m = i / KX, k = i - m * KX;
  float v = (k < 576) ? W_ih[m * 576 + k] : W_hh[m * 256 + (k - 576)];
  Wc[i] = f2bf(v);
}

// ---------------- t=0 prologue: write r-part of X for step 0
__global__ void k_init(const float* __restrict__ data, const float* __restrict__ W_r,
                       const float* __restrict__ b_r, unsigned short* __restrict__ Xbf) {
  int gid = blockIdx.x * 256 + threadIdx.x;   // n*64 + l
  int n = gid >> 6, l = gid & 63;
  float x0 = data[(n * T_) * 2 + 0];
  float x1 = data[(n * T_) * 2 + 1];
  Xbf[n * KX + l] = f2bf(fmaxf(x0 * W_r[l * 2] + x1 * W_r[l * 2 + 1] + b_r[l], 0.f));
}

// ---------------- social: e = relu(mask-scatter(hW) + b_e) -> Xbf (permuted)
__global__ __launch_bounds__(256) void k_social(
    const float* __restrict__ data, const float* __restrict__ hW,
    const float* __restrict__ b_e, unsigned short* __restrict__ Xbf, int t) {
  int b  = blockIdx.x >> 4;          // batch
  int ig = blockIdx.x & 15;          // row group (8 rows)
  __shared__ float sx[A_], sy[A_];
  __shared__ float shw[A_ * ES];     // 16 KB
  __shared__ float acc[8][16 * ES];  // 16 KB
  int tid = threadIdx.x;
  if (tid < A_) {
    sx[tid] = data[((b * A_ + tid) * T_ + t) * 2 + 0];
    sy[tid] = data[((b * A_ + tid) * T_ + t) * 2 + 1];
  }
  for (int i = tid; i < A_ * ES; i += 256) shw[i] = hW[b * A_ * ES + i];
  for (int i = tid; i < 8 * 16 * ES; i += 256) ((float*)acc)[i] = 0.f;
  __syncthreads();

  int half = tid >> 5;               // 0..7 : row within group
  int lane = tid & 31;               // c
  int irow = ig * 8 + half;
  float xi = sx[irow], yi = sy[irow];
  float* accr = acc[half];
  if (xi >= 0.f) {
    for (int j = 0; j < A_; ++j) {
      if (j == irow) continue;
      float xj = sx[j];
      if (xj < 0.f) continue;
      float dx = xi - xj, dy = yi - sy[j];
      unsigned bx = 0, by = 0;
      bx |= (dx >= 8.f   && dx <= 16.f) ? 1u : 0u;
      bx |= (dx >= 0.f   && dx <= 8.f ) ? 2u : 0u;
      bx |= (dx >= -8.f  && dx <= 0.f ) ? 4u : 0u;
      bx |= (dx >= -16.f && dx <= -8.f) ? 8u : 0u;
      if (!bx) continue;
      by |= (dy >= -16.f && dy <= -8.f) ? 1u : 0u;
      by |= (dy >= -8.f  && dy <= 0.f ) ? 2u : 0u;
      by |= (dy >= 0.f   && dy <= 8.f ) ? 4u : 0u;
      by |= (dy >= 8.f   && dy <= 16.f) ? 8u : 0u;
      if (!by) continue;
      float hv = shw[j * ES + lane];
      unsigned m16 = 0, ty = by;
      while (ty) { int gy = __ffs(ty) - 1; ty &= ty - 1; m16 |= bx << (gy * 4); }
      while (m16) {
        int g = __ffs(m16) - 1; m16 &= m16 - 1;
        accr[g * ES + lane] += hv;
      }
    }
  }
  float be = b_e[lane];
  int hi = irow >> 4;
  int klo = (irow & 15) * ES + lane;
  for (int g = 0; g < 16; ++g) {
    float e = fmaxf(accr[g * ES + lane] + be, 0.f);
    int a_out = g * 8 + hi;
    Xbf[(b * A_ + a_out) * KX + 64 + klo] = f2bf(e);
  }
}

// ---------------- gates = Xbf @ Wc^T, LDS-staged (BM=128, BN=64, BK=32)
__global__ __launch_bounds__(256) void k_gemm(
    const unsigned short* __restrict__ Xbf, const unsigned short* __restrict__ Wc,
    float* __restrict__ gates) {
  __shared__ unsigned short sA[128 * 32];   // 8 KB
  __shared__ unsigned short sB[64 * 32];    // 4 KB
  int bid = blockIdx.x;
  int tn = bid & 15, tm = bid >> 4;         // 32 row-tiles x 16 col-tiles
  int row0 = tm * 128, col0 = tn * 64;
  int tid = threadIdx.x;
  int lane = tid & 63;
  int w = tid >> 6;
  int wr = w >> 1, wc = w & 1;              // 2x2 wave grid: 64x32 per wave
  int lr = lane & 15, lk = (lane >> 4) * 8;

  const unsigned short* gA0 = Xbf + (size_t)(row0 + (tid >> 2)) * KX + (tid & 3) * 8;
  const unsigned short* gA1 = Xbf + (size_t)(row0 + 64 + (tid >> 2)) * KX + (tid & 3) * 8;
  const unsigned short* gB  = Wc  + (size_t)(col0 + (tid >> 2)) * KX + (tid & 3) * 8;
  unsigned short* lA0 = sA + tid * 8;
  unsigned short* lA1 = sA + 2048 + tid * 8;
  unsigned short* lB  = sB + tid * 8;

  f4_t acc[4][2];
  #pragma unroll
  for (int m = 0; m < 4; ++m)
    #pragma unroll
    for (int n = 0; n < 2; ++n) acc[m][n] = (f4_t){0.f, 0.f, 0.f, 0.f};

  for (int kt = 0; kt < KX / 32; ++kt) {
    __syncthreads();
    gload16(gA0 + kt * 32, lA0);
    gload16(gA1 + kt * 32, lA1);
    gload16(gB  + kt * 32, lB);
    __syncthreads();
    bf8_t a[4], b[2];
    #pragma unroll
    for (int m = 0; m < 4; ++m)
      a[m] = *(const bf8_t*)&sA[(wr * 64 + m * 16 + lr) * 32 + lk];
    #pragma unroll
    for (int n = 0; n < 2; ++n)
      b[n] = *(const bf8_t*)&sB[(wc * 32 + n * 16 + lr) * 32 + lk];
    #pragma unroll
    for (int m = 0; m < 4; ++m)
      #pragma unroll
      for (int n = 0; n < 2; ++n)
        acc[m][n] = __builtin_amdgcn_mfma_f32_16x16x32_bf16(a[m], b[n], acc[m][n], 0, 0, 0);
  }

  int crow = (lane >> 4) * 4, ccol = lane & 15;
  #pragma unroll
  for (int m = 0; m < 4; ++m)
    #pragma unroll
    for (int n = 0; n < 2; ++n)
      #pragma unroll
      for (int j = 0; j < 4; ++j)
        gates[(size_t)(row0 + wr * 64 + m * 16 + crow + j) * GD + col0 + wc * 32 + n * 16 + ccol] = acc[m][n][j];
}

// ---------------- LSTM pointwise + head + (hW, r(t), r(t+1), Xbf h-part) fused
__global__ __launch_bounds__(256) void k_point_head(
    const float* __restrict__ gates, const float* __restrict__ b_ih,
    const float* __restrict__ b_hh, const float* __restrict__ data,
    const float* __restrict__ W_r, const float* __restrict__ b_r,
    const float* __restrict__ W_e,
    float* __restrict__ cbuf, unsigned short* __restrict__ Xbf,
    float* __restrict__ hW,
    const float* __restrict__ W_p, const float* __restrict__ b_p,
    const float* __restrict__ W_p2, const float* __restrict__ b_p2,
    const float* __restrict__ W_mu, const float* __restrict__ b_mu,
    const float* __restrict__ W_sd, const float* __restrict__ b_sd,
    const float* __restrict__ W_cr, const float* __restrict__ b_cr,
    float* __restrict__ out, int t) {
  int n = blockIdx.x, q = threadIdx.x;
  __shared__ float sin2[320];        // [ r(t) | h2 ]
  __shared__ float spp[64][4];
  __shared__ float shw[32][8];
  __shared__ float sp[64];
  __shared__ float so[32];
  const float* g = gates + (size_t)n * GD;
  float ig = g[q]       + b_ih[q]       + b_hh[q];
  float fg = g[q + 256] + b_ih[q + 256] + b_hh[q + 256];
  float gg = g[q + 512] + b_ih[q + 512] + b_hh[q + 512];
  float og = g[q + 768] + b_ih[q + 768] + b_hh[q + 768];
  float c2 = sigm(fg) * cbuf[n * HS + q] + sigm(ig) * tanhf(gg);
  float h2 = sigm(og) * tanhf(c2);
  cbuf[n * HS + q] = c2;
  Xbf[n * KX + 576 + q] = f2bf(h2);     // h-part for gemm(t+1)
  sin2[64 + q] = h2;
  if (q < 64) {
    float x0 = data[(n * T_ + t) * 2 + 0];
    float x1 = data[(n * T_ + t) * 2 + 1];
    sin2[q] = fmaxf(x0 * W_r[q * 2] + x1 * W_r[q * 2 + 1] + b_r[q], 0.f);
    if (t + 1 < T_) {
      float y0 = data[(n * T_ + t + 1) * 2 + 0];
      float y1 = data[(n * T_ + t + 1) * 2 + 1];
      Xbf[n * KX + q] = f2bf(fmaxf(y0 * W_r[q * 2] + y1 * W_r[q * 2 + 1] + b_r[q], 0.f));
    }
  }
  __syncthreads();
  {
    int o = q >> 2, p = q & 3;                    // W_p: 4 partials per output
    const float* wrow = W_p + o * 320 + p * 80;
    float a = 0.f;
    #pragma unroll 16
    for (int k = 0; k < 80; ++k) a += sin2[p * 80 + k] * wrow[k];
    spp[o][p] = a;
  }
  {
    int c = q >> 3, p = q & 7;                    // hW = h2 @ W_e^T: 8 partials
    const float* we = W_e + c * HS + p * 32;
    float a = 0.f;
    #pragma unroll 8
    for (int k = 0; k < 32; ++k) a += sin2[64 + p * 32 + k] * we[k];
    shw[c][p] = a;
  }
  __syncthreads();
  if (q < 64) {
    sp[q] = spp[q][0] + spp[q][1] + spp[q][2] + spp[q][3] + b_p[q];
  } else if (q < 96) {
    int c = q - 64;
    hW[n * ES + c] = shw[c][0] + shw[c][1] + shw[c][2] + shw[c][3]
                   + shw[c][4] + shw[c][5] + shw[c][6] + shw[c][7];
  }
  __syncthreads();
  if (q < 32) {
    const float* w2 = W_p2 + q * 64;
    float a = b_p2[q];
    #pragma unroll 16
    for (int k = 0; k < 64; ++k) a += sp[k] * w2[k];
    so[q] = a;
  }
  __syncthreads();
  if (q < 5) {
    const float* wv; float bv;
    if      (q == 0) { wv = W_mu;      bv = b_mu[0]; }
    else if (q == 1) { wv = W_mu + 32; bv = b_mu[1]; }
    else if (q == 2) { wv = W_sd;      bv = b_sd[0]; }
    else if (q == 3) { wv = W_sd + 32; bv = b_sd[1]; }
    else             { wv = W_cr;      bv = b_cr[0]; }
    float a = bv;
    #pragma unroll 8
    for (int k = 0; k < 32; ++k) a += so[k] * wv[k];
    if      (q < 2) out[(n * T_ + t) * 2 + q] = a;                             // mu
    else if (q < 4) out[N_ * T_ * 2 + (n * T_ + t) * 2 + (q - 2)] = __expf(a); // sd
    else            out[N_ * T_ * 4 + n * T_ + t] = tanhf(a);                  // cr
  }
}

extern "C" void kernel_launch(void* const* d_in, const int* in_sizes, int n_in,
                              void* d_out, int out_size, void* d_ws, size_t ws_size,
                              hipStream_t stream) {
  const float* data = (const float*)d_in[0];
  const float* W_r  = (const float*)d_in[2];
  const float* b_r  = (const float*)d_in[3];
  const float* W_e  = (const float*)d_in[4];
  const float* b_e  = (const float*)d_in[5];
  const float* W_ih = (const float*)d_in[6];
  const float* W_hh = (const float*)d_in[7];
  const float* b_ih = (const float*)d_in[8];
  const float* b_hh = (const float*)d_in[9];
  const float* W_p  = (const float*)d_in[10];
  const float* b_p  = (const float*)d_in[11];
  const float* W_p2 = (const float*)d_in[12];
  const float* b_p2 = (const float*)d_in[13];
  const float* W_mu = (const float*)d_in[14];
  const float* b_mu = (const float*)d_in[15];
  const float* W_sd = (const float*)d_in[16];
  const float* b_sd = (const float*)d_in[17];
  const float* W_cr = (const float*)d_in[18];
  const float* b_cr = (const float*)d_in[19];
  float* out = (float*)d_out;

  char* ws = (char*)d_ws;
  float* cbuf  = (float*)(ws);                      // 4 MB
  float* hW    = (float*)(ws + (4u  << 20));        // 0.5 MB
  float* gates = (float*)(ws + (5u  << 20));        // 16 MB
  unsigned short* Xbf = (unsigned short*)(ws + (21u << 20)); // 6.8 MB
  unsigned short* Wc  = (unsigned short*)(ws + (28u << 20)); // 1.7 MB

  hipMemsetAsync(cbuf, 0, (size_t)N_ * HS * sizeof(float), stream);
  hipMemsetAsync(hW,   0, (size_t)N_ * ES * sizeof(float), stream);
  hipMemsetAsync(Xbf,  0, (size_t)N_ * KX * sizeof(unsigned short), stream);

  k_wcat<<<(GD * KX + 255) / 256, 256, 0, stream>>>(W_ih, W_hh, Wc);
  k_init<<<N_ * RS / 256, 256, 0, stream>>>(data, W_r, b_r, Xbf);

  for (int t = 0; t < T_; ++t) {
    k_social<<<512, 256, 0, stream>>>(data, hW, b_e, Xbf, t);
    k_gemm<<<512, 256, 0, stream>>>(Xbf, Wc, gates);
    k_point_head<<<4096, 256, 0, stream>>>(gates, b_ih, b_hh, data, W_r, b_r, W_e,
        cbuf, Xbf, hW,
        W_p, b_p, W_p2, b_p2, W_mu, b_mu, W_sd, b_sd, W_cr, b_cr, out, t);
  }
}

// Round 3
// 5380.573 us; speedup vs baseline: 1.9397x; 1.3631x over previous
//
#include <hip/hip_runtime.h>
#include <hip/hip_bf16.h>

#define B_  32
#define A_  128
#define T_  64
#define N_  4096        // B_*A_
#define HS  256
#define ES  32
#define RS  64
#define KX  832         // 64 (r) + 512 (e) + 256 (h)
#define GD  1024        // 4*HS

typedef __attribute__((ext_vector_type(8))) short bf8_t;            // 8 x bf16
typedef __attribute__((ext_vector_type(8))) unsigned short u16x8;
typedef __attribute__((ext_vector_type(4))) float f4_t;             // mfma acc

__device__ __forceinline__ unsigned short f2bf(float x) {
  union { float f; unsigned u; } v; v.f = x;
  unsigned u = v.u;
  u += 0x7fffu + ((u >> 16) & 1u);     // round-to-nearest-even
  return (unsigned short)(u >> 16);
}
__device__ __forceinline__ float sigm(float x) { return 1.f / (1.f + __expf(-x)); }

__device__ __forceinline__ void gload16(const void* g, void* l) {
  __builtin_amdgcn_global_load_lds((const __attribute__((address_space(1))) void*)g,
                                   (__attribute__((address_space(3))) void*)l, 16, 0, 0);
}

// ---- Wc (permuted: row j = 64*nb+16*g+q <-> orig g*256+nb*16+q) + fused bias
__global__ void k_wcat(const float* __restrict__ W_ih, const float* __restrict__ W_hh,
                       const float* __restrict__ b_ih, const float* __restrict__ b_hh,
                       unsigned short* __restrict__ Wc, float* __restrict__ bsum) {
  int i = blockIdx.x * 256 + threadIdx.x;
  if (i < GD * KX) {
    int mp = i / KX, k = i - mp * KX;
    int nb = mp >> 6, rem = mp & 63, g = rem >> 4, q = rem & 15;
    int mo = g * 256 + nb * 16 + q;
    float v = (k < 576) ? W_ih[mo * 576 + k] : W_hh[mo * 256 + (k - 576)];
    Wc[i] = f2bf(v);
  } else if (i < GD * KX + GD) {
    int j = i - GD * KX;
    int nb = j >> 6, rem = j & 63, g = rem >> 4, q = rem & 15;
    int mo = g * 256 + nb * 16 + q;
    bsum[j] = b_ih[mo] + b_hh[mo];
  }
}

// ---- collapse head: Whead[5][320] = [W_mu;W_sd;W_cr] @ W_p2 @ W_p, bhead[5]
__global__ __launch_bounds__(256) void k_head(
    const float* __restrict__ W_p, const float* __restrict__ b_p,
    const float* __restrict__ W_p2, const float* __restrict__ b_p2,
    const float* __restrict__ W_mu, const float* __restrict__ b_mu,
    const float* __restrict__ W_sd, const float* __restrict__ b_sd,
    const float* __restrict__ W_cr, const float* __restrict__ b_cr,
    float* __restrict__ Whead, float* __restrict__ bhead) {
  __shared__ float M[32][320];   // W_p2 @ W_p
  __shared__ float t2[32];
  int tid = threadIdx.x;
  for (int idx = tid; idx < 32 * 320; idx += 256) {
    int r = idx / 320, k = idx - r * 320;
    float a = 0.f;
    for (int j = 0; j < 64; ++j) a += W_p2[r * 64 + j] * W_p[j * 320 + k];
    M[r][k] = a;
  }
  if (tid < 32) {
    float a = b_p2[tid];
    for (int j = 0; j < 64; ++j) a += W_p2[tid * 64 + j] * b_p[j];
    t2[tid] = a;
  }
  __syncthreads();
  for (int idx = tid; idx < 5 * 320; idx += 256) {
    int o = idx / 320, k = idx - o * 320;
    const float* Wo = (o < 2) ? W_mu + o * 32 : (o < 4) ? W_sd + (o - 2) * 32 : W_cr;
    float a = 0.f;
    for (int c = 0; c < 32; ++c) a += Wo[c] * M[c][k];
    Whead[idx] = a;
  }
  if (tid < 5) {
    const float* Wo = (tid < 2) ? W_mu + tid * 32 : (tid < 4) ? W_sd + (tid - 2) * 32 : W_cr;
    float b0 = (tid < 2) ? b_mu[tid] : (tid < 4) ? b_sd[tid - 2] : b_cr[0];
    float a = b0;
    for (int c = 0; c < 32; ++c) a += Wo[c] * t2[c];
    bhead[tid] = a;
  }
}

// ---- t=0 prologue: r(0) into X0
__global__ void k_init(const float* __restrict__ data, const float* __restrict__ W_r,
                       const float* __restrict__ b_r, unsigned short* __restrict__ Xbf) {
  int gid = blockIdx.x * 256 + threadIdx.x;   // n*64 + l
  int n = gid >> 6, l = gid & 63;
  float x0 = data[(n * T_) * 2 + 0];
  float x1 = data[(n * T_) * 2 + 1];
  Xbf[n * KX + l] = f2bf(fmaxf(x0 * W_r[l * 2] + x1 * W_r[l * 2 + 1] + b_r[l], 0.f));
}

// ---- social: e = relu(mask-scatter(hW) + b_e) -> Xcur (permuted)
__global__ __launch_bounds__(256) void k_social(
    const float* __restrict__ data, const float* __restrict__ hW,
    const float* __restrict__ b_e, unsigned short* __restrict__ Xbf, int t) {
  int b  = blockIdx.x >> 4;
  int ig = blockIdx.x & 15;
  __shared__ float sx[A_], sy[A_];
  __shared__ float shw[A_ * ES];
  __shared__ float acc[8][16 * ES];
  int tid = threadIdx.x;
  if (tid < A_) {
    sx[tid] = data[((b * A_ + tid) * T_ + t) * 2 + 0];
    sy[tid] = data[((b * A_ + tid) * T_ + t) * 2 + 1];
  }
  for (int i = tid; i < A_ * ES; i += 256) shw[i] = hW[b * A_ * ES + i];
  for (int i = tid; i < 8 * 16 * ES; i += 256) ((float*)acc)[i] = 0.f;
  __syncthreads();

  int half = tid >> 5;
  int lane = tid & 31;
  int irow = ig * 8 + half;
  float xi = sx[irow], yi = sy[irow];
  float* accr = acc[half];
  if (xi >= 0.f) {
    for (int j = 0; j < A_; ++j) {
      if (j == irow) continue;
      float xj = sx[j];
      if (xj < 0.f) continue;
      float dx = xi - xj, dy = yi - sy[j];
      unsigned bx = 0, by = 0;
      bx |= (dx >= 8.f   && dx <= 16.f) ? 1u : 0u;
      bx |= (dx >= 0.f   && dx <= 8.f ) ? 2u : 0u;
      bx |= (dx >= -8.f  && dx <= 0.f ) ? 4u : 0u;
      bx |= (dx >= -16.f && dx <= -8.f) ? 8u : 0u;
      if (!bx) continue;
      by |= (dy >= -16.f && dy <= -8.f) ? 1u : 0u;
      by |= (dy >= -8.f  && dy <= 0.f ) ? 2u : 0u;
      by |= (dy >= 0.f   && dy <= 8.f ) ? 4u : 0u;
      by |= (dy >= 8.f   && dy <= 16.f) ? 8u : 0u;
      if (!by) continue;
      float hv = shw[j * ES + lane];
      unsigned m16 = 0, ty = by;
      while (ty) { int gy = __ffs(ty) - 1; ty &= ty - 1; m16 |= bx << (gy * 4); }
      while (m16) {
        int g = __ffs(m16) - 1; m16 &= m16 - 1;
        accr[g * ES + lane] += hv;
      }
    }
  }
  float be = b_e[lane];
  int hi = irow >> 4;
  int klo = (irow & 15) * ES + lane;
  for (int g = 0; g < 16; ++g) {
    float e = fmaxf(accr[g * ES + lane] + be, 0.f);
    int a_out = g * 8 + hi;
    Xbf[(b * A_ + a_out) * KX + 64 + klo] = f2bf(e);
  }
}

// ---- gates GEMM (permuted cols) + fused LSTM pointwise
// BM=128, BN=64(=4 gates x 16 ch), BK=32; writes cbuf, hbuf, Xnext h-part.
__global__ __launch_bounds__(256) void k_gemm_lstm(
    const unsigned short* __restrict__ Xcur, const unsigned short* __restrict__ Wc,
    const float* __restrict__ bsum,
    float* __restrict__ cbuf, float* __restrict__ hbuf,
    unsigned short* __restrict__ Xnext) {
  __shared__ unsigned short sA[128 * 32];   // 8 KB
  __shared__ unsigned short sB[64 * 32];    // 4 KB
  __shared__ float gtile[128][65];          // 33.3 KB (padded)
  __shared__ float sbias[64];
  int bid = blockIdx.x;
  int tn = bid & 15, tm = bid >> 4;
  int row0 = tm * 128, col0 = tn * 64;
  int tid = threadIdx.x;
  int lane = tid & 63;
  int w = tid >> 6;
  int wr = w >> 1, wc = w & 1;              // 2x2 waves: 64x32 each
  int lr = lane & 15, lk = (lane >> 4) * 8;

  if (tid < 64) sbias[tid] = bsum[col0 + tid];

  const unsigned short* gA0 = Xcur + (size_t)(row0 + (tid >> 2)) * KX + (tid & 3) * 8;
  const unsigned short* gA1 = Xcur + (size_t)(row0 + 64 + (tid >> 2)) * KX + (tid & 3) * 8;
  const unsigned short* gB  = Wc  + (size_t)(col0 + (tid >> 2)) * KX + (tid & 3) * 8;
  unsigned short* lA0 = sA + tid * 8;
  unsigned short* lA1 = sA + 2048 + tid * 8;
  unsigned short* lB  = sB + tid * 8;

  f4_t acc[4][2];
  #pragma unroll
  for (int m = 0; m < 4; ++m)
    #pragma unroll
    for (int n = 0; n < 2; ++n) acc[m][n] = (f4_t){0.f, 0.f, 0.f, 0.f};

  for (int kt = 0; kt < KX / 32; ++kt) {
    __syncthreads();
    gload16(gA0 + kt * 32, lA0);
    gload16(gA1 + kt * 32, lA1);
    gload16(gB  + kt * 32, lB);
    __syncthreads();
    bf8_t a[4], b[2];
    #pragma unroll
    for (int m = 0; m < 4; ++m)
      a[m] = *(const bf8_t*)&sA[(wr * 64 + m * 16 + lr) * 32 + lk];
    #pragma unroll
    for (int n = 0; n < 2; ++n)
      b[n] = *(const bf8_t*)&sB[(wc * 32 + n * 16 + lr) * 32 + lk];
    #pragma unroll
    for (int m = 0; m < 4; ++m)
      #pragma unroll
      for (int n = 0; n < 2; ++n)
        acc[m][n] = __builtin_amdgcn_mfma_f32_16x16x32_bf16(a[m], b[n], acc[m][n], 0, 0, 0);
  }

  int crow = (lane >> 4) * 4, ccol = lane & 15;
  #pragma unroll
  for (int m = 0; m < 4; ++m)
    #pragma unroll
    for (int n = 0; n < 2; ++n)
      #pragma unroll
      for (int j = 0; j < 4; ++j)
        gtile[wr * 64 + m * 16 + crow + j][wc * 32 + n * 16 + ccol] = acc[m][n][j];
  __syncthreads();

  // LSTM pointwise: thread -> row = tid>>1, channels q0..q0+7 (q0 = (tid&1)*8)
  int row = tid >> 1;
  int q0 = (tid & 1) * 8;
  int grow = row0 + row;
  int ch0 = tn * 16 + q0;
  float4* cb = (float4*)(cbuf + (size_t)grow * HS + ch0);
  float4* hb = (float4*)(hbuf + (size_t)grow * HS + ch0);
  float4 cv0 = cb[0], cv1 = cb[1];
  float cold[8] = {cv0.x, cv0.y, cv0.z, cv0.w, cv1.x, cv1.y, cv1.z, cv1.w};
  float c2v[8], h2v[8];
  #pragma unroll
  for (int k = 0; k < 8; ++k) {
    int q = q0 + k;
    float ig = gtile[row][q]      + sbias[q];
    float fg = gtile[row][16 + q] + sbias[16 + q];
    float gg = gtile[row][32 + q] + sbias[32 + q];
    float og = gtile[row][48 + q] + sbias[48 + q];
    float c2 = sigm(fg) * cold[k] + sigm(ig) * tanhf(gg);
    c2v[k] = c2;
    h2v[k] = sigm(og) * tanhf(c2);
  }
  cb[0] = (float4){c2v[0], c2v[1], c2v[2], c2v[3]};
  cb[1] = (float4){c2v[4], c2v[5], c2v[6], c2v[7]};
  hb[0] = (float4){h2v[0], h2v[1], h2v[2], h2v[3]};
  hb[1] = (float4){h2v[4], h2v[5], h2v[6], h2v[7]};
  u16x8 hx;
  #pragma unroll
  for (int k = 0; k < 8; ++k) hx[k] = f2bf(h2v[k]);
  *(u16x8*)(Xnext + (size_t)grow * KX + 576 + ch0) = hx;
}

// ---- tail: hW = h2 @ W_e^T; head (collapsed 5x320); r(t+1) -> Xnext
__global__ __launch_bounds__(256) void k_tail(
    const float* __restrict__ hbuf, const float* __restrict__ data,
    const float* __restrict__ W_r, const float* __restrict__ b_r,
    const float* __restrict__ W_e, const float* __restrict__ Whead,
    const float* __restrict__ bhead,
    float* __restrict__ hW, unsigned short* __restrict__ Xnext,
    float* __restrict__ out, int t) {
  __shared__ float sWeT[256][33];   // W_e transposed, padded
  __shared__ float sWh[5][320];
  __shared__ float sbh[5];
  __shared__ float sh[4][256];
  __shared__ float sr[4][64];
  int tid = threadIdx.x;
  #pragma unroll 4
  for (int c = 0; c < 32; ++c) sWeT[tid][c] = W_e[c * HS + tid];
  for (int i = tid; i < 5 * 320; i += 256) ((float*)sWh)[i] = Whead[i];
  if (tid < 5) sbh[tid] = bhead[tid];
  __syncthreads();

  int wv = tid >> 6, lane = tid & 63;
  int c32 = lane & 31, ph = lane >> 5;
  int wgid = blockIdx.x * 4 + wv;          // 0..1023

  for (int rep = 0; rep < 4; ++rep) {
    int n = wgid * 4 + rep;
    // stage h2 row + r into LDS (wave-private)
    float4 hv = ((const float4*)(hbuf + (size_t)n * HS))[lane];
    ((float4*)sh[wv])[lane] = hv;
    float x0 = data[(n * T_ + t) * 2 + 0];
    float x1 = data[(n * T_ + t) * 2 + 1];
    sr[wv][lane] = fmaxf(x0 * W_r[lane * 2] + x1 * W_r[lane * 2 + 1] + b_r[lane], 0.f);
    if (t + 1 < T_) {
      float y0 = data[(n * T_ + t + 1) * 2 + 0];
      float y1 = data[(n * T_ + t + 1) * 2 + 1];
      Xnext[(size_t)n * KX + lane] =
          f2bf(fmaxf(y0 * W_r[lane * 2] + y1 * W_r[lane * 2 + 1] + b_r[lane], 0.f));
    }
    // hW[c] = sum_k h2[k] * W_e[c][k]   (two 128-halves, shfl-reduce)
    float a = 0.f;
    #pragma unroll 8
    for (int k2 = 0; k2 < 128; ++k2) {
      int k = ph * 128 + k2;
      a += sh[wv][k] * sWeT[k][c32];
    }
    a += __shfl_xor(a, 32);
    if (lane < 32) hW[(size_t)n * ES + c32] = a;
    // head: 5 outputs over inp2 = [r | h2] (320)
    float a0 = 0.f, a1 = 0.f, a2 = 0.f, a3 = 0.f, a4 = 0.f;
    #pragma unroll
    for (int jj = 0; jj < 5; ++jj) {
      int k = lane + 64 * jj;
      float v = (jj == 0) ? sr[wv][lane] : sh[wv][k - 64];
      a0 += v * sWh[0][k];
      a1 += v * sWh[1][k];
      a2 += v * sWh[2][k];
      a3 += v * sWh[3][k];
      a4 += v * sWh[4][k];
    }
    #pragma unroll
    for (int off = 32; off; off >>= 1) {
      a0 += __shfl_xor(a0, off);
      a1 += __shfl_xor(a1, off);
      a2 += __shfl_xor(a2, off);
      a3 += __shfl_xor(a3, off);
      a4 += __shfl_xor(a4, off);
    }
    if (lane == 0) {
      out[(n * T_ + t) * 2 + 0] = a0 + sbh[0];
      out[(n * T_ + t) * 2 + 1] = a1 + sbh[1];
      out[N_ * T_ * 2 + (n * T_ + t) * 2 + 0] = __expf(a2 + sbh[2]);
      out[N_ * T_ * 2 + (n * T_ + t) * 2 + 1] = __expf(a3 + sbh[3]);
      out[N_ * T_ * 4 + n * T_ + t] = tanhf(a4 + sbh[4]);
    }
  }
}

extern "C" void kernel_launch(void* const* d_in, const int* in_sizes, int n_in,
                              void* d_out, int out_size, void* d_ws, size_t ws_size,
                              hipStream_t stream) {
  const float* data = (const float*)d_in[0];
  const float* W_r  = (const float*)d_in[2];
  const float* b_r  = (const float*)d_in[3];
  const float* W_e  = (const float*)d_in[4];
  const float* b_e  = (const float*)d_in[5];
  const float* W_ih = (const float*)d_in[6];
  const float* W_hh = (const float*)d_in[7];
  const float* b_ih = (const float*)d_in[8];
  const float* b_hh = (const float*)d_in[9];
  const float* W_p  = (const float*)d_in[10];
  const float* b_p  = (const float*)d_in[11];
  const float* W_p2 = (const float*)d_in[12];
  const float* b_p2 = (const float*)d_in[13];
  const float* W_mu = (const float*)d_in[14];
  const float* b_mu = (const float*)d_in[15];
  const float* W_sd = (const float*)d_in[16];
  const float* b_sd = (const float*)d_in[17];
  const float* W_cr = (const float*)d_in[18];
  const float* b_cr = (const float*)d_in[19];
  float* out = (float*)d_out;

  char* ws = (char*)d_ws;
  float* cbuf  = (float*)(ws);                               // 4 MB
  float* hbuf  = (float*)(ws + (4u  << 20));                 // 4 MB
  float* hW    = (float*)(ws + (8u  << 20));                 // 0.5 MB
  unsigned short* Xbf0 = (unsigned short*)(ws + (9u  << 20)); // 6.5 MB
  unsigned short* Xbf1 = (unsigned short*)(ws + (16u << 20)); // 6.5 MB
  unsigned short* Wc   = (unsigned short*)(ws + (23u << 20)); // 1.7 MB
  float* bsum  = (float*)(ws + (25u << 20));                 // 4 KB
  float* Whead = (float*)(ws + (25u << 20) + 8192);          // 6.4 KB
  float* bhead = (float*)(ws + (25u << 20) + 16384);         // 20 B

  hipMemsetAsync(cbuf, 0, (size_t)N_ * HS * sizeof(float), stream);
  hipMemsetAsync(hW,   0, (size_t)N_ * ES * sizeof(float), stream);
  hipMemsetAsync(Xbf0, 0, (size_t)N_ * KX * sizeof(unsigned short), stream);
  hipMemsetAsync(Xbf1, 0, (size_t)N_ * KX * sizeof(unsigned short), stream);

  k_wcat<<<(GD * KX + GD + 255) / 256, 256, 0, stream>>>(W_ih, W_hh, b_ih, b_hh, Wc, bsum);
  k_head<<<1, 256, 0, stream>>>(W_p, b_p, W_p2, b_p2, W_mu, b_mu, W_sd, b_sd, W_cr, b_cr,
                                Whead, bhead);
  k_init<<<N_ * RS / 256, 256, 0, stream>>>(data, W_r, b_r, Xbf0);

  for (int t = 0; t < T_; ++t) {
    unsigned short* Xcur  = (t & 1) ? Xbf1 : Xbf0;
    unsigned short* Xnext = (t & 1) ? Xbf0 : Xbf1;
    k_social<<<512, 256, 0, stream>>>(data, hW, b_e, Xcur, t);
    k_gemm_lstm<<<512, 256, 0, stream>>>(Xcur, Wc, bsum, cbuf, hbuf, Xnext);
    k_tail<<<256, 256, 0, stream>>>(hbuf, data, W_r, b_r, W_e, Whead, bhead,
                                    hW, Xnext, out, t);
  }
}

// Round 4
// 5226.158 us; speedup vs baseline: 1.9970x; 1.0295x over previous
//
#include <hip/hip_runtime.h>
#include <hip/hip_bf16.h>

#define B_  32
#define A_  128
#define T_  64
#define N_  4096        // B_*A_
#define HS  256
#define ES  32
#define RS  64
#define KX  832         // 64 (r) + 512 (e) + 256 (h)
#define GD  1024        // 4*HS
#define NKT 26          // KX/32

typedef __attribute__((ext_vector_type(8))) short bf8_t;            // 8 x bf16
typedef __attribute__((ext_vector_type(8))) unsigned short u16x8;
typedef __attribute__((ext_vector_type(4))) float f4_t;             // mfma acc

__device__ __forceinline__ unsigned short f2bf(float x) {
  union { float f; unsigned u; } v; v.f = x;
  unsigned u = v.u;
  u += 0x7fffu + ((u >> 16) & 1u);     // round-to-nearest-even
  return (unsigned short)(u >> 16);
}
__device__ __forceinline__ float sigm(float x) { return 1.f / (1.f + __expf(-x)); }

__device__ __forceinline__ void gload16(const void* g, void* l) {
  __builtin_amdgcn_global_load_lds((const __attribute__((address_space(1))) void*)g,
                                   (__attribute__((address_space(3))) void*)l, 16, 0, 0);
}

// ---- Wc (permuted: row j = 64*nb+16*g+q <-> orig g*256+nb*16+q) + fused bias
__global__ void k_wcat(const float* __restrict__ W_ih, const float* __restrict__ W_hh,
                       const float* __restrict__ b_ih, const float* __restrict__ b_hh,
                       unsigned short* __restrict__ Wc, float* __restrict__ bsum) {
  int i = blockIdx.x * 256 + threadIdx.x;
  if (i < GD * KX) {
    int mp = i / KX, k = i - mp * KX;
    int nb = mp >> 6, rem = mp & 63, g = rem >> 4, q = rem & 15;
    int mo = g * 256 + nb * 16 + q;
    float v = (k < 576) ? W_ih[mo * 576 + k] : W_hh[mo * 256 + (k - 576)];
    Wc[i] = f2bf(v);
  } else if (i < GD * KX + GD) {
    int j = i - GD * KX;
    int nb = j >> 6, rem = j & 63, g = rem >> 4, q = rem & 15;
    int mo = g * 256 + nb * 16 + q;
    bsum[j] = b_ih[mo] + b_hh[mo];
  }
}

// ---- collapsed head: Whead[o][320] = (Wo @ W_p2) @ W_p   (5 blocks x 320 thr)
__global__ __launch_bounds__(320) void k_head(
    const float* __restrict__ W_p, const float* __restrict__ b_p,
    const float* __restrict__ W_p2, const float* __restrict__ b_p2,
    const float* __restrict__ W_mu, const float* __restrict__ b_mu,
    const float* __restrict__ W_sd, const float* __restrict__ b_sd,
    const float* __restrict__ W_cr, const float* __restrict__ b_cr,
    float* __restrict__ Whead, float* __restrict__ bhead) {
  int o = blockIdx.x, tid = threadIdx.x;
  __shared__ float to[64];
  const float* Wo = (o < 2) ? W_mu + o * 32 : (o < 4) ? W_sd + (o - 2) * 32 : W_cr;
  if (tid < 64) {
    float a = 0.f;
    #pragma unroll 8
    for (int c = 0; c < 32; ++c) a += Wo[c] * W_p2[c * 64 + tid];
    to[tid] = a;
  }
  __syncthreads();
  float a = 0.f;
  #pragma unroll 8
  for (int j = 0; j < 64; ++j) a += to[j] * W_p[j * 320 + tid];
  Whead[o * 320 + tid] = a;
  if (tid == 0) {
    float b0 = (o < 2) ? b_mu[o] : (o < 4) ? b_sd[o - 2] : b_cr[0];
    float acc = b0;
    for (int c = 0; c < 32; ++c) acc += Wo[c] * b_p2[c];
    for (int j = 0; j < 64; ++j) acc += to[j] * b_p[j];
    bhead[o] = acc;
  }
}

// ---- t=0 prologue: r(0) into X0
__global__ void k_init(const float* __restrict__ data, const float* __restrict__ W_r,
                       const float* __restrict__ b_r, unsigned short* __restrict__ Xbf) {
  int gid = blockIdx.x * 256 + threadIdx.x;   // n*64 + l
  int n = gid >> 6, l = gid & 63;
  float x0 = data[(n * T_) * 2 + 0];
  float x1 = data[(n * T_) * 2 + 1];
  Xbf[n * KX + l] = f2bf(fmaxf(x0 * W_r[l * 2] + x1 * W_r[l * 2 + 1] + b_r[l], 0.f));
}

// ---- social: e = relu(mask-scatter(hW) + b_e) -> Xcur (permuted)
__global__ __launch_bounds__(256) void k_social(
    const float* __restrict__ data, const float* __restrict__ hW,
    const float* __restrict__ b_e, unsigned short* __restrict__ Xbf, int t) {
  int b  = blockIdx.x >> 4;
  int ig = blockIdx.x & 15;
  __shared__ float sx[A_], sy[A_];
  __shared__ float shw[A_ * ES];
  __shared__ float acc[8][16 * ES];
  int tid = threadIdx.x;
  if (tid < A_) {
    sx[tid] = data[((b * A_ + tid) * T_ + t) * 2 + 0];
    sy[tid] = data[((b * A_ + tid) * T_ + t) * 2 + 1];
  }
  for (int i = tid; i < A_ * ES; i += 256) shw[i] = hW[b * A_ * ES + i];
  for (int i = tid; i < 8 * 16 * ES; i += 256) ((float*)acc)[i] = 0.f;
  __syncthreads();

  int half = tid >> 5;
  int lane = tid & 31;
  int irow = ig * 8 + half;
  float xi = sx[irow], yi = sy[irow];
  float* accr = acc[half];
  if (xi >= 0.f) {
    for (int j = 0; j < A_; ++j) {
      if (j == irow) continue;
      float xj = sx[j];
      if (xj < 0.f) continue;
      float dx = xi - xj, dy = yi - sy[j];
      unsigned bx = 0, by = 0;
      bx |= (dx >= 8.f   && dx <= 16.f) ? 1u : 0u;
      bx |= (dx >= 0.f   && dx <= 8.f ) ? 2u : 0u;
      bx |= (dx >= -8.f  && dx <= 0.f ) ? 4u : 0u;
      bx |= (dx >= -16.f && dx <= -8.f) ? 8u : 0u;
      if (!bx) continue;
      by |= (dy >= -16.f && dy <= -8.f) ? 1u : 0u;
      by |= (dy >= -8.f  && dy <= 0.f ) ? 2u : 0u;
      by |= (dy >= 0.f   && dy <= 8.f ) ? 4u : 0u;
      by |= (dy >= 8.f   && dy <= 16.f) ? 8u : 0u;
      if (!by) continue;
      float hv = shw[j * ES + lane];
      unsigned m16 = 0, ty = by;
      while (ty) { int gy = __ffs(ty) - 1; ty &= ty - 1; m16 |= bx << (gy * 4); }
      while (m16) {
        int g = __ffs(m16) - 1; m16 &= m16 - 1;
        accr[g * ES + lane] += hv;
      }
    }
  }
  float be = b_e[lane];
  int hi = irow >> 4;
  int klo = (irow & 15) * ES + lane;
  for (int g = 0; g < 16; ++g) {
    float e = fmaxf(accr[g * ES + lane] + be, 0.f);
    int a_out = g * 8 + hi;
    Xbf[(b * A_ + a_out) * KX + 64 + klo] = f2bf(e);
  }
}

// ---- gates GEMM (permuted cols) + fused LSTM pointwise
// BM=128, BN=64, BK=32; double-buffered LDS staging (issue-early), chunk-XOR
// swizzle (c' = c ^ ((row>>1)&3)) applied via pre-swizzled global source +
// swizzled ds_read (linear LDS dest for global_load_lds).
__global__ __launch_bounds__(256) void k_gemm_lstm(
    const unsigned short* __restrict__ Xcur, const unsigned short* __restrict__ Wc,
    const float* __restrict__ bsum,
    float* __restrict__ cbuf, float* __restrict__ hbuf,
    unsigned short* __restrict__ Xnext) {
  // union: [ sA0 8K | sB0 4K | sA1 8K | sB1 4K ] (24K)  vs  gtile 128x65 f32 (33.3K)
  __shared__ __align__(16) char smem[33280];
  __shared__ float sbias[64];
  unsigned short* sA0 = (unsigned short*)smem;
  unsigned short* sB0 = (unsigned short*)(smem + 8192);
  unsigned short* sA1 = (unsigned short*)(smem + 12288);
  unsigned short* sB1 = (unsigned short*)(smem + 20480);
  float (*gtile)[65] = (float (*)[65])smem;

  int bid = blockIdx.x;
  int tn = bid & 15, tm = bid >> 4;
  int row0 = tm * 128, col0 = tn * 64;
  int tid = threadIdx.x;
  int lane = tid & 63;
  int w = tid >> 6;
  int wr = w >> 1, wc = w & 1;              // 2x2 waves: 64x32 each
  int lr = lane & 15, lh = lane >> 4;

  if (tid < 64) sbias[tid] = bsum[col0 + tid];

  // staging: thread -> LDS row srow, chunk-slot schunk; global chunk swizzled
  int srow = tid >> 2, schunk = tid & 3;
  int gch = (schunk ^ ((srow >> 1) & 3)) * 8;
  const unsigned short* gA0 = Xcur + (size_t)(row0 + srow) * KX + gch;
  const unsigned short* gA1 = Xcur + (size_t)(row0 + 64 + srow) * KX + gch;
  const unsigned short* gB  = Wc  + (size_t)(col0 + srow) * KX + gch;

  // frag read offsets (shorts), swizzled chunk
  int swz = (lh ^ ((lr >> 1) & 3)) * 8;
  int aoff[4], boff[2];
  #pragma unroll
  for (int m = 0; m < 4; ++m) aoff[m] = (wr * 64 + m * 16 + lr) * 32 + swz;
  #pragma unroll
  for (int n = 0; n < 2; ++n) boff[n] = (wc * 32 + n * 16 + lr) * 32 + swz;

  f4_t acc[4][2];
  #pragma unroll
  for (int m = 0; m < 4; ++m)
    #pragma unroll
    for (int n = 0; n < 2; ++n) acc[m][n] = (f4_t){0.f, 0.f, 0.f, 0.f};

#define STAGE(pA, pB, kt) do { \
    gload16(gA0 + (kt) * 32, (pA) + tid * 8); \
    gload16(gA1 + (kt) * 32, (pA) + 2048 + tid * 8); \
    gload16(gB  + (kt) * 32, (pB) + tid * 8); \
  } while (0)

#define COMPUTE(pA, pB) do { \
    bf8_t a_[4], b_[2]; \
    _Pragma("unroll") for (int m = 0; m < 4; ++m) a_[m] = *(const bf8_t*)((pA) + aoff[m]); \
    _Pragma("unroll") for (int n = 0; n < 2; ++n) b_[n] = *(const bf8_t*)((pB) + boff[n]); \
    _Pragma("unroll") for (int m = 0; m < 4; ++m) \
      _Pragma("unroll") for (int n = 0; n < 2; ++n) \
        acc[m][n] = __builtin_amdgcn_mfma_f32_16x16x32_bf16(a_[m], b_[n], acc[m][n], 0, 0, 0); \
  } while (0)

  STAGE(sA0, sB0, 0);
  __syncthreads();
  #pragma unroll 1
  for (int kt = 0; kt < NKT; kt += 2) {
    STAGE(sA1, sB1, kt + 1);          // kt+1 <= 25 always (NKT even)
    COMPUTE(sA0, sB0);
    __syncthreads();
    if (kt + 2 < NKT) STAGE(sA0, sB0, kt + 2);
    COMPUTE(sA1, sB1);
    __syncthreads();
  }
#undef STAGE
#undef COMPUTE

  int crow = (lane >> 4) * 4, ccol = lane & 15;
  #pragma unroll
  for (int m = 0; m < 4; ++m)
    #pragma unroll
    for (int n = 0; n < 2; ++n)
      #pragma unroll
      for (int j = 0; j < 4; ++j)
        gtile[wr * 64 + m * 16 + crow + j][wc * 32 + n * 16 + ccol] = acc[m][n][j];
  __syncthreads();

  // LSTM pointwise: thread -> row = tid>>1, channels q0..q0+7 (q0 = (tid&1)*8)
  int row = tid >> 1;
  int q0 = (tid & 1) * 8;
  int grow = row0 + row;
  int ch0 = tn * 16 + q0;
  float4* cb = (float4*)(cbuf + (size_t)grow * HS + ch0);
  float4* hb = (float4*)(hbuf + (size_t)grow * HS + ch0);
  float4 cv0 = cb[0], cv1 = cb[1];
  float cold[8] = {cv0.x, cv0.y, cv0.z, cv0.w, cv1.x, cv1.y, cv1.z, cv1.w};
  float c2v[8], h2v[8];
  #pragma unroll
  for (int k = 0; k < 8; ++k) {
    int q = q0 + k;
    float ig = gtile[row][q]      + sbias[q];
    float fg = gtile[row][16 + q] + sbias[16 + q];
    float gg = gtile[row][32 + q] + sbias[32 + q];
    float og = gtile[row][48 + q] + sbias[48 + q];
    float c2 = sigm(fg) * cold[k] + sigm(ig) * tanhf(gg);
    c2v[k] = c2;
    h2v[k] = sigm(og) * tanhf(c2);
  }
  cb[0] = (float4){c2v[0], c2v[1], c2v[2], c2v[3]};
  cb[1] = (float4){c2v[4], c2v[5], c2v[6], c2v[7]};
  hb[0] = (float4){h2v[0], h2v[1], h2v[2], h2v[3]};
  hb[1] = (float4){h2v[4], h2v[5], h2v[6], h2v[7]};
  u16x8 hx;
  #pragma unroll
  for (int k = 0; k < 8; ++k) hx[k] = f2bf(h2v[k]);
  *(u16x8*)(Xnext + (size_t)grow * KX + 576 + ch0) = hx;
}

// ---- tail: hW = h2 @ W_e^T; head (collapsed 5x320); r(t+1) -> Xnext
__global__ __launch_bounds__(256) void k_tail(
    const float* __restrict__ hbuf, const float* __restrict__ data,
    const float* __restrict__ W_r, const float* __restrict__ b_r,
    const float* __restrict__ W_e, const float* __restrict__ Whead,
    const float* __restrict__ bhead,
    float* __restrict__ hW, unsigned short* __restrict__ Xnext,
    float* __restrict__ out, int t) {
  __shared__ float sWeT[256][33];   // W_e transposed, padded
  __shared__ float sWh[5][320];
  __shared__ float sbh[5];
  __shared__ float sh[4][256];
  __shared__ float sr[4][64];
  int tid = threadIdx.x;
  #pragma unroll 4
  for (int c = 0; c < 32; ++c) sWeT[tid][c] = W_e[c * HS + tid];
  for (int i = tid; i < 5 * 320; i += 256) ((float*)sWh)[i] = Whead[i];
  if (tid < 5) sbh[tid] = bhead[tid];
  __syncthreads();

  int wv = tid >> 6, lane = tid & 63;
  int c32 = lane & 31, ph = lane >> 5;
  int wgid = blockIdx.x * 4 + wv;          // 0..1023

  for (int rep = 0; rep < 4; ++rep) {
    int n = wgid * 4 + rep;
    float4 hv = ((const float4*)(hbuf + (size_t)n * HS))[lane];
    ((float4*)sh[wv])[lane] = hv;
    float x0 = data[(n * T_ + t) * 2 + 0];
    float x1 = data[(n * T_ + t) * 2 + 1];
    sr[wv][lane] = fmaxf(x0 * W_r[lane * 2] + x1 * W_r[lane * 2 + 1] + b_r[lane], 0.f);
    if (t + 1 < T_) {
      float y0 = data[(n * T_ + t + 1) * 2 + 0];
      float y1 = data[(n * T_ + t + 1) * 2 + 1];
      Xnext[(size_t)n * KX + lane] =
          f2bf(fmaxf(y0 * W_r[lane * 2] + y1 * W_r[lane * 2 + 1] + b_r[lane], 0.f));
    }
    float a = 0.f;
    #pragma unroll 8
    for (int k2 = 0; k2 < 128; ++k2) {
      int k = ph * 128 + k2;
      a += sh[wv][k] * sWeT[k][c32];
    }
    a += __shfl_xor(a, 32);
    if (lane < 32) hW[(size_t)n * ES + c32] = a;
    float a0 = 0.f, a1 = 0.f, a2 = 0.f, a3 = 0.f, a4 = 0.f;
    #pragma unroll
    for (int jj = 0; jj < 5; ++jj) {
      int k = lane + 64 * jj;
      float v = (jj == 0) ? sr[wv][lane] : sh[wv][k - 64];
      a0 += v * sWh[0][k];
      a1 += v * sWh[1][k];
      a2 += v * sWh[2][k];
      a3 += v * sWh[3][k];
      a4 += v * sWh[4][k];
    }
    #pragma unroll
    for (int off = 32; off; off >>= 1) {
      a0 += __shfl_xor(a0, off);
      a1 += __shfl_xor(a1, off);
      a2 += __shfl_xor(a2, off);
      a3 += __shfl_xor(a3, off);
      a4 += __shfl_xor(a4, off);
    }
    if (lane == 0) {
      out[(n * T_ + t) * 2 + 0] = a0 + sbh[0];
      out[(n * T_ + t) * 2 + 1] = a1 + sbh[1];
      out[N_ * T_ * 2 + (n * T_ + t) * 2 + 0] = __expf(a2 + sbh[2]);
      out[N_ * T_ * 2 + (n * T_ + t) * 2 + 1] = __expf(a3 + sbh[3]);
      out[N_ * T_ * 4 + n * T_ + t] = tanhf(a4 + sbh[4]);
    }
  }
}

extern "C" void kernel_launch(void* const* d_in, const int* in_sizes, int n_in,
                              void* d_out, int out_size, void* d_ws, size_t ws_size,
                              hipStream_t stream) {
  const float* data = (const float*)d_in[0];
  const float* W_r  = (const float*)d_in[2];
  const float* b_r  = (const float*)d_in[3];
  const float* W_e  = (const float*)d_in[4];
  const float* b_e  = (const float*)d_in[5];
  const float* W_ih = (const float*)d_in[6];
  const float* W_hh = (const float*)d_in[7];
  const float* b_ih = (const float*)d_in[8];
  const float* b_hh = (const float*)d_in[9];
  const float* W_p  = (const float*)d_in[10];
  const float* b_p  = (const float*)d_in[11];
  const float* W_p2 = (const float*)d_in[12];
  const float* b_p2 = (const float*)d_in[13];
  const float* W_mu = (const float*)d_in[14];
  const float* b_mu = (const float*)d_in[15];
  const float* W_sd = (const float*)d_in[16];
  const float* b_sd = (const float*)d_in[17];
  const float* W_cr = (const float*)d_in[18];
  const float* b_cr = (const float*)d_in[19];
  float* out = (float*)d_out;

  char* ws = (char*)d_ws;
  float* cbuf  = (float*)(ws);                               // 4 MB
  float* hbuf  = (float*)(ws + (4u  << 20));                 // 4 MB
  float* hW    = (float*)(ws + (8u  << 20));                 // 0.5 MB
  unsigned short* Xbf0 = (unsigned short*)(ws + (9u  << 20)); // 6.5 MB
  unsigned short* Xbf1 = (unsigned short*)(ws + (16u << 20)); // 6.5 MB
  unsigned short* Wc   = (unsigned short*)(ws + (23u << 20)); // 1.7 MB
  float* bsum  = (float*)(ws + (25u << 20));                 // 4 KB
  float* Whead = (float*)(ws + (25u << 20) + 8192);          // 6.4 KB
  float* bhead = (float*)(ws + (25u << 20) + 16384);         // 20 B

  hipMemsetAsync(cbuf, 0, (size_t)N_ * HS * sizeof(float), stream);
  hipMemsetAsync(hW,   0, (size_t)N_ * ES * sizeof(float), stream);
  hipMemsetAsync(Xbf0, 0, (size_t)N_ * KX * sizeof(unsigned short), stream);
  hipMemsetAsync(Xbf1, 0, (size_t)N_ * KX * sizeof(unsigned short), stream);

  k_wcat<<<(GD * KX + GD + 255) / 256, 256, 0, stream>>>(W_ih, W_hh, b_ih, b_hh, Wc, bsum);
  k_head<<<5, 320, 0, stream>>>(W_p, b_p, W_p2, b_p2, W_mu, b_mu, W_sd, b_sd, W_cr, b_cr,
                                Whead, bhead);
  k_init<<<N_ * RS / 256, 256, 0, stream>>>(data, W_r, b_r, Xbf0);

  for (int t = 0; t < T_; ++t) {
    unsigned short* Xcur  = (t & 1) ? Xbf1 : Xbf0;
    unsigned short* Xnext = (t & 1) ? Xbf0 : Xbf1;
    k_social<<<512, 256, 0, stream>>>(data, hW, b_e, Xcur, t);
    k_gemm_lstm<<<512, 256, 0, stream>>>(Xcur, Wc, bsum, cbuf, hbuf, Xnext);
    k_tail<<<256, 256, 0, stream>>>(hbuf, data, W_r, b_r, W_e, Whead, bhead,
                                    hW, Xnext, out, t);
  }
}

// Round 5
// 3046.344 us; speedup vs baseline: 3.4259x; 1.7156x over previous
//
#include <hip/hip_runtime.h>
#include <hip/hip_bf16.h>

#define B_  32
#define A_  128
#define T_  64
#define N_  4096        // B_*A_
#define HS  256
#define ES  32
#define RS  64
#define KX  832         // 64 (r) + 512 (e) + 256 (h)
#define GD  1024        // 4*HS
#define NKT 26          // KX/32

typedef __attribute__((ext_vector_type(8))) short bf8_t;            // 8 x bf16
typedef __attribute__((ext_vector_type(8))) unsigned short u16x8;
typedef __attribute__((ext_vector_type(4))) float f4_t;             // mfma acc
typedef __attribute__((ext_vector_type(2))) float f2_t;

__device__ __forceinline__ unsigned short f2bf(float x) {
  union { float f; unsigned u; } v; v.f = x;
  unsigned u = v.u;
  u += 0x7fffu + ((u >> 16) & 1u);     // round-to-nearest-even
  return (unsigned short)(u >> 16);
}
__device__ __forceinline__ float sigm(float x) { return 1.f / (1.f + __expf(-x)); }

__device__ __forceinline__ void gload16(const void* g, void* l) {
  __builtin_amdgcn_global_load_lds((const __attribute__((address_space(1))) void*)g,
                                   (__attribute__((address_space(3))) void*)l, 16, 0, 0);
}

// ---- Wc (permuted: row j = 64*nb+16*g+q <-> orig g*256+nb*16+q) + fused bias
__global__ void k_wcat(const float* __restrict__ W_ih, const float* __restrict__ W_hh,
                       const float* __restrict__ b_ih, const float* __restrict__ b_hh,
                       unsigned short* __restrict__ Wc, float* __restrict__ bsum) {
  int i = blockIdx.x * 256 + threadIdx.x;
  if (i < GD * KX) {
    int mp = i / KX, k = i - mp * KX;
    int nb = mp >> 6, rem = mp & 63, g = rem >> 4, q = rem & 15;
    int mo = g * 256 + nb * 16 + q;
    float v = (k < 576) ? W_ih[mo * 576 + k] : W_hh[mo * 256 + (k - 576)];
    Wc[i] = f2bf(v);
  } else if (i < GD * KX + GD) {
    int j = i - GD * KX;
    int nb = j >> 6, rem = j & 63, g = rem >> 4, q = rem & 15;
    int mo = g * 256 + nb * 16 + q;
    bsum[j] = b_ih[mo] + b_hh[mo];
  }
}

// ---- collapsed head: Whead[o][320] = (Wo @ W_p2) @ W_p   (5 blocks x 320 thr)
__global__ __launch_bounds__(320) void k_head(
    const float* __restrict__ W_p, const float* __restrict__ b_p,
    const float* __restrict__ W_p2, const float* __restrict__ b_p2,
    const float* __restrict__ W_mu, const float* __restrict__ b_mu,
    const float* __restrict__ W_sd, const float* __restrict__ b_sd,
    const float* __restrict__ W_cr, const float* __restrict__ b_cr,
    float* __restrict__ Whead, float* __restrict__ bhead) {
  int o = blockIdx.x, tid = threadIdx.x;
  __shared__ float to[64];
  const float* Wo = (o < 2) ? W_mu + o * 32 : (o < 4) ? W_sd + (o - 2) * 32 : W_cr;
  if (tid < 64) {
    float a = 0.f;
    #pragma unroll 8
    for (int c = 0; c < 32; ++c) a += Wo[c] * W_p2[c * 64 + tid];
    to[tid] = a;
  }
  __syncthreads();
  float a = 0.f;
  #pragma unroll 8
  for (int j = 0; j < 64; ++j) a += to[j] * W_p[j * 320 + tid];
  Whead[o * 320 + tid] = a;
  if (tid == 0) {
    float b0 = (o < 2) ? b_mu[o] : (o < 4) ? b_sd[o - 2] : b_cr[0];
    float acc = b0;
    for (int c = 0; c < 32; ++c) acc += Wo[c] * b_p2[c];
    for (int j = 0; j < 64; ++j) acc += to[j] * b_p[j];
    bhead[o] = acc;
  }
}

// ---- t=0 prologue: r(0) into X0
__global__ void k_init(const float* __restrict__ data, const float* __restrict__ W_r,
                       const float* __restrict__ b_r, unsigned short* __restrict__ Xbf) {
  int gid = blockIdx.x * 256 + threadIdx.x;   // n*64 + l
  int n = gid >> 6, l = gid & 63;
  float x0 = data[(n * T_) * 2 + 0];
  float x1 = data[(n * T_) * 2 + 1];
  Xbf[n * KX + l] = f2bf(fmaxf(x0 * W_r[l * 2] + x1 * W_r[l * 2 + 1] + b_r[l], 0.f));
}

// ---- social: e = relu(mask-scatter(hW) + b_e) -> Xcur (permuted)
// Outer-product form: mask16(i,j) = bx(dx) (x) by(dy). Phase 1 computes the
// 4+4 0/1 indicators once per (row,j) into LDS; phase 2 accumulates 16
// register accumulators per (row,channel) thread via f2 (paired-j) FMAs.
__global__ __launch_bounds__(256) void k_social(
    const float* __restrict__ data, const float* __restrict__ hW,
    const float* __restrict__ b_e, unsigned short* __restrict__ Xbf, int t) {
  int b  = blockIdx.x >> 4;
  int ig = blockIdx.x & 15;
  __shared__ float sx[A_], sy[A_];
  __shared__ float shw2[64 * 64];     // [jp][c][sub]  16 KB
  __shared__ float smx[8][64][8];     // [r][jp][gx*2+sub]  16 KB
  __shared__ float smy[8][64][8];     // [r][jp][gy*2+sub]  16 KB
  int tid = threadIdx.x;
  if (tid < A_) {
    sx[tid] = data[((b * A_ + tid) * T_ + t) * 2 + 0];
    sy[tid] = data[((b * A_ + tid) * T_ + t) * 2 + 1];
  }
  for (int i = tid; i < A_ * ES; i += 256) {
    int j = i >> 5, c = i & 31;
    shw2[(j >> 1) * 64 + c * 2 + (j & 1)] = hW[b * A_ * ES + i];
  }
  __syncthreads();

  // phase 1: indicator build (512 units = 8 rows x 64 j-pairs)
  for (int u = tid; u < 512; u += 256) {
    int r = u >> 6, jp = u & 63;
    int irow = ig * 8 + r;
    float xi = sx[irow], yi = sy[irow];
    bool acti = xi >= 0.f;
    float m0[4], m1[4], n0[4], n1[4];
    #pragma unroll
    for (int s = 0; s < 2; ++s) {
      int j = jp * 2 + s;
      float xj = sx[j], yj = sy[j];
      bool v = acti && (xj >= 0.f) && (j != irow);
      float dx = xi - xj, dy = yi - yj;
      float* mm = s ? m1 : m0;
      float* nn = s ? n1 : n0;
      mm[0] = (v && dx >= 8.f   && dx <= 16.f) ? 1.f : 0.f;
      mm[1] = (v && dx >= 0.f   && dx <= 8.f ) ? 1.f : 0.f;
      mm[2] = (v && dx >= -8.f  && dx <= 0.f ) ? 1.f : 0.f;
      mm[3] = (v && dx >= -16.f && dx <= -8.f) ? 1.f : 0.f;
      nn[0] = (dy >= -16.f && dy <= -8.f) ? 1.f : 0.f;
      nn[1] = (dy >= -8.f  && dy <= 0.f ) ? 1.f : 0.f;
      nn[2] = (dy >= 0.f   && dy <= 8.f ) ? 1.f : 0.f;
      nn[3] = (dy >= 8.f   && dy <= 16.f) ? 1.f : 0.f;
    }
    float4* px = (float4*)&smx[r][jp][0];
    px[0] = (float4){m0[0], m1[0], m0[1], m1[1]};
    px[1] = (float4){m0[2], m1[2], m0[3], m1[3]};
    float4* py = (float4*)&smy[r][jp][0];
    py[0] = (float4){n0[0], n1[0], n0[1], n1[1]};
    py[1] = (float4){n0[2], n1[2], n0[3], n1[3]};
  }
  __syncthreads();

  // phase 2: register accumulate, f2 (paired j) math
  int half = tid >> 5;               // row within group
  int lane = tid & 31;               // channel
  f2_t acc[16];
  #pragma unroll
  for (int g = 0; g < 16; ++g) acc[g] = (f2_t){0.f, 0.f};
  #pragma unroll 2
  for (int jp = 0; jp < 64; ++jp) {
    f2_t hv = *(const f2_t*)&shw2[jp * 64 + lane * 2];
    float4 xa = ((const float4*)&smx[half][jp][0])[0];
    float4 xb = ((const float4*)&smx[half][jp][0])[1];
    float4 ya = ((const float4*)&smy[half][jp][0])[0];
    float4 yb = ((const float4*)&smy[half][jp][0])[1];
    f2_t mx[4] = {(f2_t){xa.x, xa.y}, (f2_t){xa.z, xa.w},
                  (f2_t){xb.x, xb.y}, (f2_t){xb.z, xb.w}};
    f2_t p[4]  = {(f2_t){ya.x, ya.y} * hv, (f2_t){ya.z, ya.w} * hv,
                  (f2_t){yb.x, yb.y} * hv, (f2_t){yb.z, yb.w} * hv};
    #pragma unroll
    for (int gy = 0; gy < 4; ++gy)
      #pragma unroll
      for (int gx = 0; gx < 4; ++gx)
        acc[gy * 4 + gx] += mx[gx] * p[gy];
  }

  // epilogue: e -> Xbf at torch-reshape-permuted location
  int irow = ig * 8 + half;
  float be = b_e[lane];
  int hi = irow >> 4;
  int klo = (irow & 15) * ES + lane;
  #pragma unroll
  for (int g = 0; g < 16; ++g) {
    float e = fmaxf(acc[g][0] + acc[g][1] + be, 0.f);
    int a_out = g * 8 + hi;
    Xbf[(b * A_ + a_out) * KX + 64 + klo] = f2bf(e);
  }
}

// ---- gates GEMM (permuted cols) + fused LSTM pointwise
__global__ __launch_bounds__(256) void k_gemm_lstm(
    const unsigned short* __restrict__ Xcur, const unsigned short* __restrict__ Wc,
    const float* __restrict__ bsum,
    float* __restrict__ cbuf, float* __restrict__ hbuf,
    unsigned short* __restrict__ Xnext) {
  // union: [ sA0 8K | sB0 4K | sA1 8K | sB1 4K ] (24K)  vs  gtile 128x65 f32 (33.3K)
  __shared__ __align__(16) char smem[33280];
  __shared__ float sbias[64];
  unsigned short* sA0 = (unsigned short*)smem;
  unsigned short* sB0 = (unsigned short*)(smem + 8192);
  unsigned short* sA1 = (unsigned short*)(smem + 12288);
  unsigned short* sB1 = (unsigned short*)(smem + 20480);
  float (*gtile)[65] = (float (*)[65])smem;

  int bid = blockIdx.x;
  int tn = bid & 15, tm = bid >> 4;
  int row0 = tm * 128, col0 = tn * 64;
  int tid = threadIdx.x;
  int lane = tid & 63;
  int w = tid >> 6;
  int wr = w >> 1, wc = w & 1;              // 2x2 waves: 64x32 each
  int lr = lane & 15, lh = lane >> 4;

  if (tid < 64) sbias[tid] = bsum[col0 + tid];

  int srow = tid >> 2, schunk = tid & 3;
  int gch = (schunk ^ ((srow >> 1) & 3)) * 8;
  const unsigned short* gA0 = Xcur + (size_t)(row0 + srow) * KX + gch;
  const unsigned short* gA1 = Xcur + (size_t)(row0 + 64 + srow) * KX + gch;
  const unsigned short* gB  = Wc  + (size_t)(col0 + srow) * KX + gch;

  int swz = (lh ^ ((lr >> 1) & 3)) * 8;
  int aoff[4], boff[2];
  #pragma unroll
  for (int m = 0; m < 4; ++m) aoff[m] = (wr * 64 + m * 16 + lr) * 32 + swz;
  #pragma unroll
  for (int n = 0; n < 2; ++n) boff[n] = (wc * 32 + n * 16 + lr) * 32 + swz;

  f4_t acc[4][2];
  #pragma unroll
  for (int m = 0; m < 4; ++m)
    #pragma unroll
    for (int n = 0; n < 2; ++n) acc[m][n] = (f4_t){0.f, 0.f, 0.f, 0.f};

#define STAGE(pA, pB, kt) do { \
    gload16(gA0 + (kt) * 32, (pA) + tid * 8); \
    gload16(gA1 + (kt) * 32, (pA) + 2048 + tid * 8); \
    gload16(gB  + (kt) * 32, (pB) + tid * 8); \
  } while (0)

#define COMPUTE(pA, pB) do { \
    bf8_t a_[4], b_[2]; \
    _Pragma("unroll") for (int m = 0; m < 4; ++m) a_[m] = *(const bf8_t*)((pA) + aoff[m]); \
    _Pragma("unroll") for (int n = 0; n < 2; ++n) b_[n] = *(const bf8_t*)((pB) + boff[n]); \
    _Pragma("unroll") for (int m = 0; m < 4; ++m) \
      _Pragma("unroll") for (int n = 0; n < 2; ++n) \
        acc[m][n] = __builtin_amdgcn_mfma_f32_16x16x32_bf16(a_[m], b_[n], acc[m][n], 0, 0, 0); \
  } while (0)

  STAGE(sA0, sB0, 0);
  __syncthreads();
  #pragma unroll 1
  for (int kt = 0; kt < NKT; kt += 2) {
    STAGE(sA1, sB1, kt + 1);
    COMPUTE(sA0, sB0);
    __syncthreads();
    if (kt + 2 < NKT) STAGE(sA0, sB0, kt + 2);
    COMPUTE(sA1, sB1);
    __syncthreads();
  }
#undef STAGE
#undef COMPUTE

  int crow = (lane >> 4) * 4, ccol = lane & 15;
  #pragma unroll
  for (int m = 0; m < 4; ++m)
    #pragma unroll
    for (int n = 0; n < 2; ++n)
      #pragma unroll
      for (int j = 0; j < 4; ++j)
        gtile[wr * 64 + m * 16 + crow + j][wc * 32 + n * 16 + ccol] = acc[m][n][j];
  __syncthreads();

  int row = tid >> 1;
  int q0 = (tid & 1) * 8;
  int grow = row0 + row;
  int ch0 = tn * 16 + q0;
  float4* cb = (float4*)(cbuf + (size_t)grow * HS + ch0);
  float4* hb = (float4*)(hbuf + (size_t)grow * HS + ch0);
  float4 cv0 = cb[0], cv1 = cb[1];
  float cold[8] = {cv0.x, cv0.y, cv0.z, cv0.w, cv1.x, cv1.y, cv1.z, cv1.w};
  float c2v[8], h2v[8];
  #pragma unroll
  for (int k = 0; k < 8; ++k) {
    int q = q0 + k;
    float ig = gtile[row][q]      + sbias[q];
    float fg = gtile[row][16 + q] + sbias[16 + q];
    float gg = gtile[row][32 + q] + sbias[32 + q];
    float og = gtile[row][48 + q] + sbias[48 + q];
    float c2 = sigm(fg) * cold[k] + sigm(ig) * tanhf(gg);
    c2v[k] = c2;
    h2v[k] = sigm(og) * tanhf(c2);
  }
  cb[0] = (float4){c2v[0], c2v[1], c2v[2], c2v[3]};
  cb[1] = (float4){c2v[4], c2v[5], c2v[6], c2v[7]};
  hb[0] = (float4){h2v[0], h2v[1], h2v[2], h2v[3]};
  hb[1] = (float4){h2v[4], h2v[5], h2v[6], h2v[7]};
  u16x8 hx;
  #pragma unroll
  for (int k = 0; k < 8; ++k) hx[k] = f2bf(h2v[k]);
  *(u16x8*)(Xnext + (size_t)grow * KX + 576 + ch0) = hx;
}

// ---- tail: hW = h2 @ W_e^T; head (collapsed 5x320); r(t+1) -> Xnext
__global__ __launch_bounds__(256) void k_tail(
    const float* __restrict__ hbuf, const float* __restrict__ data,
    const float* __restrict__ W_r, const float* __restrict__ b_r,
    const float* __restrict__ W_e, const float* __restrict__ Whead,
    const float* __restrict__ bhead,
    float* __restrict__ hW, unsigned short* __restrict__ Xnext,
    float* __restrict__ out, int t) {
  __shared__ float sWeT[256][33];   // W_e transposed, padded
  __shared__ float sWh[5][320];
  __shared__ float sbh[5];
  __shared__ float sh[4][256];
  __shared__ float sr[4][64];
  int tid = threadIdx.x;
  #pragma unroll 4
  for (int c = 0; c < 32; ++c) sWeT[tid][c] = W_e[c * HS + tid];
  for (int i = tid; i < 5 * 320; i += 256) ((float*)sWh)[i] = Whead[i];
  if (tid < 5) sbh[tid] = bhead[tid];
  __syncthreads();

  int wv = tid >> 6, lane = tid & 63;
  int c32 = lane & 31, ph = lane >> 5;
  int wgid = blockIdx.x * 4 + wv;          // 0..1023

  for (int rep = 0; rep < 4; ++rep) {
    int n = wgid * 4 + rep;
    float4 hv = ((const float4*)(hbuf + (size_t)n * HS))[lane];
    ((float4*)sh[wv])[lane] = hv;
    float x0 = data[(n * T_ + t) * 2 + 0];
    float x1 = data[(n * T_ + t) * 2 + 1];
    sr[wv][lane] = fmaxf(x0 * W_r[lane * 2] + x1 * W_r[lane * 2 + 1] + b_r[lane], 0.f);
    if (t + 1 < T_) {
      float y0 = data[(n * T_ + t + 1) * 2 + 0];
      float y1 = data[(n * T_ + t + 1) * 2 + 1];
      Xnext[(size_t)n * KX + lane] =
          f2bf(fmaxf(y0 * W_r[lane * 2] + y1 * W_r[lane * 2 + 1] + b_r[lane], 0.f));
    }
    float a = 0.f;
    #pragma unroll 8
    for (int k2 = 0; k2 < 128; ++k2) {
      int k = ph * 128 + k2;
      a += sh[wv][k] * sWeT[k][c32];
    }
    a += __shfl_xor(a, 32);
    if (lane < 32) hW[(size_t)n * ES + c32] = a;
    float a0 = 0.f, a1 = 0.f, a2 = 0.f, a3 = 0.f, a4 = 0.f;
    #pragma unroll
    for (int jj = 0; jj < 5; ++jj) {
      int k = lane + 64 * jj;
      float v = (jj == 0) ? sr[wv][lane] : sh[wv][k - 64];
      a0 += v * sWh[0][k];
      a1 += v * sWh[1][k];
      a2 += v * sWh[2][k];
      a3 += v * sWh[3][k];
      a4 += v * sWh[4][k];
    }
    #pragma unroll
    for (int off = 32; off; off >>= 1) {
      a0 += __shfl_xor(a0, off);
      a1 += __shfl_xor(a1, off);
      a2 += __shfl_xor(a2, off);
      a3 += __shfl_xor(a3, off);
      a4 += __shfl_xor(a4, off);
    }
    if (lane == 0) {
      out[(n * T_ + t) * 2 + 0] = a0 + sbh[0];
      out[(n * T_ + t) * 2 + 1] = a1 + sbh[1];
      out[N_ * T_ * 2 + (n * T_ + t) * 2 + 0] = __expf(a2 + sbh[2]);
      out[N_ * T_ * 2 + (n * T_ + t) * 2 + 1] = __expf(a3 + sbh[3]);
      out[N_ * T_ * 4 + n * T_ + t] = tanhf(a4 + sbh[4]);
    }
  }
}

extern "C" void kernel_launch(void* const* d_in, const int* in_sizes, int n_in,
                              void* d_out, int out_size, void* d_ws, size_t ws_size,
                              hipStream_t stream) {
  const float* data = (const float*)d_in[0];
  const float* W_r  = (const float*)d_in[2];
  const float* b_r  = (const float*)d_in[3];
  const float* W_e  = (const float*)d_in[4];
  const float* b_e  = (const float*)d_in[5];
  const float* W_ih = (const float*)d_in[6];
  const float* W_hh = (const float*)d_in[7];
  const float* b_ih = (const float*)d_in[8];
  const float* b_hh = (const float*)d_in[9];
  const float* W_p  = (const float*)d_in[10];
  const float* b_p  = (const float*)d_in[11];
  const float* W_p2 = (const float*)d_in[12];
  const float* b_p2 = (const float*)d_in[13];
  const float* W_mu = (const float*)d_in[14];
  const float* b_mu = (const float*)d_in[15];
  const float* W_sd = (const float*)d_in[16];
  const float* b_sd = (const float*)d_in[17];
  const float* W_cr = (const float*)d_in[18];
  const float* b_cr = (const float*)d_in[19];
  float* out = (float*)d_out;

  char* ws = (char*)d_ws;
  float* cbuf  = (float*)(ws);                               // 4 MB
  float* hbuf  = (float*)(ws + (4u  << 20));                 // 4 MB
  float* hW    = (float*)(ws + (8u  << 20));                 // 0.5 MB
  unsigned short* Xbf0 = (unsigned short*)(ws + (9u  << 20)); // 6.5 MB
  unsigned short* Xbf1 = (unsigned short*)(ws + (16u << 20)); // 6.5 MB
  unsigned short* Wc   = (unsigned short*)(ws + (23u << 20)); // 1.7 MB
  float* bsum  = (float*)(ws + (25u << 20));                 // 4 KB
  float* Whead = (float*)(ws + (25u << 20) + 8192);          // 6.4 KB
  float* bhead = (float*)(ws + (25u << 20) + 16384);         // 20 B

  hipMemsetAsync(cbuf, 0, (size_t)N_ * HS * sizeof(float), stream);
  hipMemsetAsync(hW,   0, (size_t)N_ * ES * sizeof(float), stream);
  hipMemsetAsync(Xbf0, 0, (size_t)N_ * KX * sizeof(unsigned short), stream);
  hipMemsetAsync(Xbf1, 0, (size_t)N_ * KX * sizeof(unsigned short), stream);

  k_wcat<<<(GD * KX + GD + 255) / 256, 256, 0, stream>>>(W_ih, W_hh, b_ih, b_hh, Wc, bsum);
  k_head<<<5, 320, 0, stream>>>(W_p, b_p, W_p2, b_p2, W_mu, b_mu, W_sd, b_sd, W_cr, b_cr,
                                Whead, bhead);
  k_init<<<N_ * RS / 256, 256, 0, stream>>>(data, W_r, b_r, Xbf0);

  for (int t = 0; t < T_; ++t) {
    unsigned short* Xcur  = (t & 1) ? Xbf1 : Xbf0;
    unsigned short* Xnext = (t & 1) ? Xbf0 : Xbf1;
    k_social<<<512, 256, 0, stream>>>(data, hW, b_e, Xcur, t);
    k_gemm_lstm<<<512, 256, 0, stream>>>(Xcur, Wc, bsum, cbuf, hbuf, Xnext);
    k_tail<<<256, 256, 0, stream>>>(hbuf, data, W_r, b_r, W_e, Whead, bhead,
                                    hW, Xnext, out, t);
  }
}